// Round 6
// baseline (914.672 us; speedup 1.0000x reference)
//
#include <hip/hip_runtime.h>
#include <hip/hip_fp16.h>

#define S_LEN 512
#define BATCH 32
#define CHUNK 16

typedef _Float16 hv2  __attribute__((ext_vector_type(2)));
typedef _Float16 half8 __attribute__((ext_vector_type(8)));
typedef float    f32x4 __attribute__((ext_vector_type(4)));

__device__ __forceinline__ float dot2f(hv2 a, hv2 b, float c) {
#if __has_builtin(__builtin_amdgcn_fdot2)
    return __builtin_amdgcn_fdot2(a, b, c, false);
#else
    return c + (float)a.x * (float)b.x + (float)a.y * (float)b.y;
#endif
}

__device__ __forceinline__ float fast_tanh(float x) {
    float e = __expf(2.f * x);
    return 1.f - 2.f / (e + 1.f);
}

// Step barrier: LDS-visibility only (no vmcnt drain) — global traffic
// issued at chunk boundaries stays in flight across the step loop.
__device__ __forceinline__ void lds_barrier() {
    __asm__ volatile("s_waitcnt lgkmcnt(0)\n\ts_barrier" ::: "memory");
}
__device__ __forceinline__ void vm_drain() {
    __asm__ volatile("s_waitcnt vmcnt(0)" ::: "memory");
}

// ---------------------------------------------------------------------------
// Prep: convert to padded f16 (relu fused for emb). Zeroes flags.
// ---------------------------------------------------------------------------
#define E8   1280000   // 32000*320/8
#define W18  64000     // 320*1600/8
#define W28  12800     // 320*320/8
#define FF8  5120      // 128*320/8
#define PREP_TOTAL8 (E8 + W18 + W28 + FF8 + FF8)

__global__ __launch_bounds__(256) void k_prep(
    const float* __restrict__ emb,  const float* __restrict__ Wih1,
    const float* __restrict__ Wih2, const float* __restrict__ fc1w,
    const float* __restrict__ fc2w,
    _Float16* __restrict__ embf, _Float16* __restrict__ Wf1,
    _Float16* __restrict__ Wf2,  _Float16* __restrict__ F1,
    _Float16* __restrict__ F2,   unsigned int* __restrict__ flags)
{
    int gid = blockIdx.x * 256 + threadIdx.x;
    if (gid < 64) flags[gid] = 0u;
    if (gid >= PREP_TOTAL8) return;

    half8 v;
    _Float16* dst;

    if (gid < E8) {
        int row = gid / 40, c8 = (gid - row * 40) * 8;
        #pragma unroll
        for (int j = 0; j < 8; ++j) {
            int c = c8 + j;
            float f = (c < 300) ? emb[(size_t)row * 300 + c] : 0.f;
            v[j] = (_Float16)(f > 0.f ? f : 0.f);
        }
        dst = embf + (size_t)gid * 8;
    } else if (gid < E8 + W18) {
        int i = gid - E8;
        int row = i / 200, c8 = (i - row * 200) * 8;
        #pragma unroll
        for (int j = 0; j < 8; ++j) {
            int c = c8 + j, w = c / 320, cc = c - w * 320;
            float f = (row < 300 && cc < 300) ? Wih1[(size_t)row * 1500 + w * 300 + cc] : 0.f;
            v[j] = (_Float16)f;
        }
        dst = Wf1 + (size_t)i * 8;
    } else if (gid < E8 + W18 + W28) {
        int i = gid - E8 - W18;
        int row = i / 40, c8 = (i - row * 40) * 8;
        #pragma unroll
        for (int j = 0; j < 8; ++j) {
            int c = c8 + j;
            float f = (row < 300 && c < 300) ? Wih2[(size_t)row * 300 + c] : 0.f;
            v[j] = (_Float16)f;
        }
        dst = Wf2 + (size_t)i * 8;
    } else if (gid < E8 + W18 + W28 + FF8) {
        int i = gid - E8 - W18 - W28;
        int row = i / 40, c8 = (i - row * 40) * 8;
        #pragma unroll
        for (int j = 0; j < 8; ++j) {
            int c = c8 + j;
            v[j] = (_Float16)((c < 300) ? fc1w[(size_t)row * 300 + c] : 0.f);
        }
        dst = F1 + (size_t)i * 8;
    } else {
        int i = gid - E8 - W18 - W28 - FF8;
        int row = i / 40, c8 = (i - row * 40) * 8;
        #pragma unroll
        for (int j = 0; j < 8; ++j) {
            int c = c8 + j;
            v[j] = (_Float16)((c < 300) ? fc2w[(size_t)row * 300 + c] : 0.f);
        }
        dst = F2 + (size_t)i * 8;
    }
    *(half8*)dst = v;
}

// ---------------------------------------------------------------------------
// GEMM1 (MFMA, fused embedding gather). grid (128,2), block 256.
// ---------------------------------------------------------------------------
__global__ __launch_bounds__(256) void k_gemm1_mfma(
    const int* __restrict__ x, const _Float16* __restrict__ embf,
    const _Float16* __restrict__ Wf1, const float* __restrict__ b1,
    const float* __restrict__ b2, float* __restrict__ U)
{
    const int wid  = threadIdx.x >> 6;
    const int lane = threadIdx.x & 63;
    const int m    = lane & 15;
    const int q    = lane >> 4;
    const int r0   = blockIdx.x * 128 + wid * 32;
    const int n0   = blockIdx.y * 160;

    f32x4 acc[2][10];
    #pragma unroll
    for (int i = 0; i < 2; ++i)
        #pragma unroll
        for (int j = 0; j < 10; ++j)
            acc[i][j] = (f32x4){0.f, 0.f, 0.f, 0.f};

    const int rA = r0 + m, rB = r0 + 16 + m;
    const int xbA = ((rA & 31) * S_LEN + (rA >> 5)) * 5;
    const int xbB = ((rB & 31) * S_LEN + (rB >> 5)) * 5;

    for (int w = 0; w < 5; ++w) {
        const int idxA = x[xbA + w];
        const int idxB = x[xbB + w];
        const _Float16* ea = embf + (size_t)idxA * 320;
        const _Float16* eb = embf + (size_t)idxB * 320;
        const _Float16* wb = Wf1 + (size_t)w * 320;
        #pragma unroll
        for (int c = 0; c < 10; ++c) {
            const int k = c * 32 + q * 8;
            half8 a0 = *(const half8*)(ea + k);
            half8 a1 = *(const half8*)(eb + k);
            #pragma unroll
            for (int nt = 0; nt < 10; ++nt) {
                half8 bf = *(const half8*)(wb + (size_t)(n0 + nt * 16 + m) * 1600 + k);
                acc[0][nt] = __builtin_amdgcn_mfma_f32_16x16x32_f16(a0, bf, acc[0][nt], 0, 0, 0);
                acc[1][nt] = __builtin_amdgcn_mfma_f32_16x16x32_f16(a1, bf, acc[1][nt], 0, 0, 0);
            }
        }
    }

    #pragma unroll
    for (int nt = 0; nt < 10; ++nt) {
        const int n = n0 + nt * 16 + m;
        if (n >= 300) continue;
        const float bias = b1[n] + b2[n];
        #pragma unroll
        for (int mt = 0; mt < 2; ++mt) {
            const int rbase = r0 + mt * 16 + q * 4;
            #pragma unroll
            for (int reg = 0; reg < 4; ++reg)
                U[(size_t)(rbase + reg) * 300 + n] = acc[mt][nt][reg] + bias;
        }
    }
}

// ---------------------------------------------------------------------------
// FC (MFMA): per-wave 32x128. grid (128, 2): y = layer.
// ---------------------------------------------------------------------------
__global__ __launch_bounds__(256) void k_fc_mfma(
    const _Float16* __restrict__ H1, const _Float16* __restrict__ H2,
    const _Float16* __restrict__ F1, const _Float16* __restrict__ F2,
    const float* __restrict__ fb1, const float* __restrict__ fb2,
    float* __restrict__ out1, float* __restrict__ out2)
{
    const int layer = blockIdx.y;
    const _Float16* H = layer ? H2 : H1;
    const _Float16* F = layer ? F2 : F1;
    const float* bias = layer ? fb2 : fb1;
    float* out        = layer ? out2 : out1;

    const int wid  = threadIdx.x >> 6;
    const int lane = threadIdx.x & 63;
    const int m    = lane & 15;
    const int q    = lane >> 4;
    const int r0   = blockIdx.x * 128 + wid * 32;

    f32x4 acc[2][8];
    #pragma unroll
    for (int i = 0; i < 2; ++i)
        #pragma unroll
        for (int j = 0; j < 8; ++j)
            acc[i][j] = (f32x4){0.f, 0.f, 0.f, 0.f};

    const _Float16* ha = H + (size_t)(r0 + m) * 320;
    const _Float16* hb = H + (size_t)(r0 + 16 + m) * 320;

    #pragma unroll
    for (int c = 0; c < 10; ++c) {
        const int k = c * 32 + q * 8;
        half8 a0 = *(const half8*)(ha + k);
        half8 a1 = *(const half8*)(hb + k);
        #pragma unroll
        for (int nt = 0; nt < 8; ++nt) {
            half8 bf = *(const half8*)(F + (size_t)(nt * 16 + m) * 320 + k);
            acc[0][nt] = __builtin_amdgcn_mfma_f32_16x16x32_f16(a0, bf, acc[0][nt], 0, 0, 0);
            acc[1][nt] = __builtin_amdgcn_mfma_f32_16x16x32_f16(a1, bf, acc[1][nt], 0, 0, 0);
        }
    }

    #pragma unroll
    for (int nt = 0; nt < 8; ++nt) {
        const int n = nt * 16 + m;
        const float bv = bias[n];
        #pragma unroll
        for (int mt = 0; mt < 2; ++mt) {
            #pragma unroll
            for (int reg = 0; reg < 4; ++reg) {
                const int r = r0 + mt * 16 + q * 4 + reg;
                const int oidx = ((r & 31) * S_LEN + (r >> 5)) * 128 + n;
                out[oidx] = acc[mt][nt][reg] + bv;
            }
        }
    }
}

// ---------------------------------------------------------------------------
// Fused recurrence v3: 64 blocks x 640 threads, ONE barrier per step.
//   thread = (row = tid>>1, half = tid&1); W half-row in 76 VGPRs (f16 pairs);
//   h-segment read from LDS ring (pair/wave-broadcast b128 — conflict-free);
//   76 dot2 in 4 chains; __shfl_xor(1) combines halves (no LDS partials);
//   even thread: +u, tanh, one b16 write. Global traffic only at chunk
//   boundaries (U prefetch in regs, H bulk store, flag handshake).
// Consumer folds Wih2·h1 into a per-chunk MFMA (bias pre-added into uc).
// LDS: hc f16[16][320] @0 (10240) | uc f32[16][304] @10240 (19456)
//      | h1s f16[16][320] @29696 (10240)  -> 39936 B
// ---------------------------------------------------------------------------
#define LDS_BYTES 39936

__device__ __forceinline__ void load_u_regs(float* up, const float* __restrict__ U1,
                                            int b, int t0) {
    #pragma unroll
    for (int j = 0; j < 8; ++j) {
        int e = threadIdx.x + 640 * j;
        int row = e / 300, col = e - row * 300;
        up[j] = (e < 4800) ? U1[((size_t)((t0 + row) * BATCH + b)) * 300 + col] : 0.f;
    }
}

__global__ __launch_bounds__(640, 2) void k_rec_fused(
    const float* __restrict__ U1, const float* __restrict__ Whh1,
    const _Float16* __restrict__ Wf2, const float* __restrict__ Whh2,
    const float* __restrict__ bih2, const float* __restrict__ bhh2,
    _Float16* __restrict__ H1f, _Float16* __restrict__ H2f,
    unsigned int* __restrict__ flags)
{
    extern __shared__ char smem[];
    _Float16 (*hc)[320]  = (_Float16(*)[320])smem;
    float    (*uc)[304]  = (float(*)[304])(smem + 10240);
    _Float16 (*h1s)[320] = (_Float16(*)[320])(smem + 29696);

    const int tid  = threadIdx.x;
    const int row  = tid >> 1;     // 0..319
    const int half = tid & 1;
    const int lane = tid & 63;
    const int wid  = tid >> 6;     // 0..9
    const int lm   = lane & 15;
    const int lq   = lane >> 4;

    // zero full h ring (slot 15 = h_{-1} = 0; pad cols 300..319 stay 0)
    for (int i = tid; i < CHUNK * 320; i += 640)
        ((_Float16*)hc)[i] = (_Float16)0.f;

    // preload W half-row: cols half*152 .. +151 (f16 pairs, zero past 300)
    const bool act = row < 300;
    const float* wsrc = (blockIdx.x < 32) ? Whh1 : Whh2;
    hv2 w[76];
    {
        const float* wr = wsrc + (size_t)(act ? row : 0) * 300 + half * 152;
        #pragma unroll
        for (int j = 0; j < 76; ++j) {
            int c0 = half * 152 + 2 * j;
            hv2 p;
            p.x = (act && c0     < 300) ? (_Float16)wr[2 * j]     : (_Float16)0.f;
            p.y = (act && c0 + 1 < 300) ? (_Float16)wr[2 * j + 1] : (_Float16)0.f;
            w[j] = p;
        }
    }

    if (blockIdx.x < 32) {
        // ========================= producer: layer 1 =========================
        const int b = blockIdx.x;
        float upref[8];
        load_u_regs(upref, U1, b, 0);

        for (int c = 0; c < 32; ++c) {
            const int t0 = c * CHUNK;
            if (c > 0) {
                const int tb = t0 - CHUNK;
                {   // bulk store prev chunk H1 (1 half8 per thread)
                    int r16 = tid / 40, c8 = tid - r16 * 40;
                    half8 v = *(const half8*)&hc[r16][c8 * 8];
                    *(half8*)&H1f[((size_t)((tb + r16) * BATCH + b)) * 320 + c8 * 8] = v;
                }
            }
            #pragma unroll
            for (int j = 0; j < 8; ++j) {
                int e = tid + 640 * j;
                if (e < 4800) {
                    int r = e / 300, col = e - r * 300;
                    uc[r][col] = upref[j];
                }
            }
            if (c > 0) {
                vm_drain();
                if (tid == 0)
                    __hip_atomic_store(&flags[b], (unsigned)t0,
                                       __ATOMIC_RELEASE, __HIP_MEMORY_SCOPE_AGENT);
            }
            if (c + 1 < 32)
                load_u_regs(upref, U1, b, t0 + CHUNK);
            lds_barrier();

            for (int s = 0; s < CHUNK; ++s) {
                float uval = (row < 304) ? uc[s][row] : 0.f;  // pair-broadcast
                const half8* hp = (const half8*)&hc[(s - 1) & 15][half * 152];
                float a0 = 0.f, a1 = 0.f, a2 = 0.f, a3 = 0.f;
                #pragma unroll
                for (int jj = 0; jj < 19; ++jj) {
                    half8 q8 = hp[jj];
                    const hv2* qv = (const hv2*)&q8;
                    a0 = dot2f(w[4 * jj],     qv[0], a0);
                    a1 = dot2f(w[4 * jj + 1], qv[1], a1);
                    a2 = dot2f(w[4 * jj + 2], qv[2], a2);
                    a3 = dot2f(w[4 * jj + 3], qv[3], a3);
                }
                float acc = (a0 + a1) + (a2 + a3);
                acc += __shfl_xor(acc, 1);
                if (half == 0 && act)
                    hc[s][row] = (_Float16)fast_tanh(acc + uval);
                lds_barrier();
            }
        }
        {   // final chunk store + release
            const int tb = S_LEN - CHUNK;
            int r16 = tid / 40, c8 = tid - r16 * 40;
            half8 v = *(const half8*)&hc[r16][c8 * 8];
            *(half8*)&H1f[((size_t)((tb + r16) * BATCH + b)) * 320 + c8 * 8] = v;
            vm_drain();
            if (tid == 0)
                __hip_atomic_store(&flags[b], (unsigned)S_LEN,
                                   __ATOMIC_RELEASE, __HIP_MEMORY_SCOPE_AGENT);
        }
    } else {
        // ========================= consumer: layer 2 =========================
        const int b = blockIdx.x - 32;

        // per-wave bias regs for the two MFMA n-tiles (folded into uc)
        float bv0 = 0.f, bv1 = 0.f;
        {
            int n0 = wid * 16 + lm;
            if (n0 < 300) bv0 = bih2[n0] + bhh2[n0];
            int n1 = (wid + 10) * 16 + lm;
            if (wid + 10 < 19 && n1 < 300) bv1 = bih2[n1] + bhh2[n1];
        }

        for (int c = 0; c < 32; ++c) {
            const int t0 = c * CHUNK;
            if (c > 0) {
                const int tb = t0 - CHUNK;
                int r16 = tid / 40, c8 = tid - r16 * 40;
                half8 v = *(const half8*)&hc[r16][c8 * 8];
                *(half8*)&H2f[((size_t)((tb + r16) * BATCH + b)) * 320 + c8 * 8] = v;
            }
            if (tid == 0) {
                while (__hip_atomic_load(&flags[b], __ATOMIC_ACQUIRE,
                                         __HIP_MEMORY_SCOPE_AGENT) < (unsigned)(t0 + CHUNK))
                    __builtin_amdgcn_s_sleep(2);
            }
            __syncthreads();   // orders after poll; drains H2 stores (1/chunk)

            {   // stage h1 chunk (1 half8 per thread)
                int r16 = tid / 40, c8 = tid - r16 * 40;
                *(half8*)&h1s[r16][c8 * 8] =
                    *(const half8*)&H1f[((size_t)((t0 + r16) * BATCH + b)) * 320 + c8 * 8];
            }
            lds_barrier();

            // uc = h1s @ Wf2^T + bias  (MFMA, M=16 steps, N=304, K=320)
            #pragma unroll
            for (int rep = 0; rep < 2; ++rep) {
                const int nt = wid + rep * 10;
                if (nt < 19) {
                    f32x4 acc = (f32x4){0.f, 0.f, 0.f, 0.f};
                    const int n = nt * 16 + lm;
                    const _Float16* wrow = Wf2 + (size_t)n * 320;
                    #pragma unroll
                    for (int k0 = 0; k0 < 320; k0 += 32) {
                        half8 a  = *(const half8*)&h1s[lm][k0 + lq * 8];
                        half8 bf = *(const half8*)&wrow[k0 + lq * 8];
                        acc = __builtin_amdgcn_mfma_f32_16x16x32_f16(a, bf, acc, 0, 0, 0);
                    }
                    const float bb = rep ? bv1 : bv0;
                    #pragma unroll
                    for (int reg = 0; reg < 4; ++reg)
                        uc[lq * 4 + reg][n] = acc[reg] + bb;
                }
            }
            lds_barrier();

            for (int s = 0; s < CHUNK; ++s) {
                float uval = (row < 304) ? uc[s][row] : 0.f;
                const half8* hp = (const half8*)&hc[(s - 1) & 15][half * 152];
                float a0 = 0.f, a1 = 0.f, a2 = 0.f, a3 = 0.f;
                #pragma unroll
                for (int jj = 0; jj < 19; ++jj) {
                    half8 q8 = hp[jj];
                    const hv2* qv = (const hv2*)&q8;
                    a0 = dot2f(w[4 * jj],     qv[0], a0);
                    a1 = dot2f(w[4 * jj + 1], qv[1], a1);
                    a2 = dot2f(w[4 * jj + 2], qv[2], a2);
                    a3 = dot2f(w[4 * jj + 3], qv[3], a3);
                }
                float acc = (a0 + a1) + (a2 + a3);
                acc += __shfl_xor(acc, 1);
                if (half == 0 && act)
                    hc[s][row] = (_Float16)fast_tanh(acc + uval);
                lds_barrier();
            }
        }
        {   // final H2 chunk store
            const int tb = S_LEN - CHUNK;
            int r16 = tid / 40, c8 = tid - r16 * 40;
            half8 v = *(const half8*)&hc[r16][c8 * 8];
            *(half8*)&H2f[((size_t)((tb + r16) * BATCH + b)) * 320 + c8 * 8] = v;
        }
    }
}

extern "C" void kernel_launch(void* const* d_in, const int* in_sizes, int n_in,
                              void* d_out, int out_size, void* d_ws, size_t ws_size,
                              hipStream_t stream) {
    const int*   x     = (const int*)d_in[0];
    const float* emb   = (const float*)d_in[1];
    const float* Wih1  = (const float*)d_in[2];
    const float* Whh1  = (const float*)d_in[3];
    const float* bih1  = (const float*)d_in[4];
    const float* bhh1  = (const float*)d_in[5];
    const float* Wih2  = (const float*)d_in[6];
    const float* Whh2  = (const float*)d_in[7];
    const float* bih2  = (const float*)d_in[8];
    const float* bhh2  = (const float*)d_in[9];
    const float* fc1w  = (const float*)d_in[10];
    const float* fc1b  = (const float*)d_in[11];
    const float* fc2w  = (const float*)d_in[12];
    const float* fc2b  = (const float*)d_in[13];

    float* out1 = (float*)d_out;
    float* out2 = out1 + (size_t)16384 * 128;

    char* w = (char*)d_ws;
    float*        U1    = (float*)w;                     // 19,660,800
    _Float16*     H1    = (_Float16*)(w + 19660800);     // 10,485,760
    _Float16*     Wf1   = (_Float16*)(w + 30146560);     //  1,024,000
    _Float16*     Wf2   = (_Float16*)(w + 31170560);     //    204,800
    _Float16*     F1    = (_Float16*)(w + 31375360);     //     81,920
    _Float16*     F2    = (_Float16*)(w + 31457280);     //     81,920
    unsigned int* flags = (unsigned int*)(w + 31539200); //        256
    _Float16*     EMBF  = (_Float16*)(w + 31539456);     // 20,480,000
    _Float16*     H2    = EMBF;  // reuse: gemm1 done with EMBF before rec writes H2

    const int prep_blocks = (PREP_TOTAL8 + 255) / 256;
    k_prep<<<prep_blocks, 256, 0, stream>>>(emb, Wih1, Wih2, fc1w, fc2w,
                                            EMBF, Wf1, Wf2, F1, F2, flags);

    dim3 g(128, 2);
    k_gemm1_mfma<<<g, 256, 0, stream>>>(x, EMBF, Wf1, bih1, bhh1, U1);
    k_rec_fused<<<64, 640, LDS_BYTES, stream>>>(U1, Whh1, Wf2, Whh2, bih2, bhh2,
                                                H1, H2, flags);
    k_fc_mfma<<<g, 256, 0, stream>>>(H1, H2, F1, F2, fc1b, fc2b, out1, out2);
}